// Round 1
// baseline (155.809 us; speedup 1.0000x reference)
//
#include <hip/hip_runtime.h>
#include <math.h>

#define BB 8
#define SS 64
#define NN 512
#define EE 32

// Kernel 1: compute ti' = x^T @ Wi^T + b_w  and  tj = x^T @ Wj^T
// One thread per (b, n). x reads coalesced (consecutive n -> consecutive addr).
__global__ __launch_bounds__(256) void proj_kernel(
    const float* __restrict__ x,   // (B, S, N)
    const float* __restrict__ W,   // (E, 2S)
    const float* __restrict__ b_w, // (E,)
    float* __restrict__ tip,       // (B, N, E)  ti + b_w
    float* __restrict__ tjp)       // (B, N, E)
{
    __shared__ float sW[EE * 2 * SS]; // 4096 floats
    int t = threadIdx.x;
    for (int k = t; k < EE * 2 * SS; k += 256) sW[k] = W[k];
    __syncthreads();

    int gid = blockIdx.x * 256 + t;      // b*N + n
    int b = gid >> 9;
    int n = gid & (NN - 1);

    float ai[EE];
    float aj[EE];
#pragma unroll
    for (int e = 0; e < EE; ++e) { ai[e] = 0.f; aj[e] = 0.f; }

    const float* xb = x + (size_t)b * SS * NN + n;
    for (int s = 0; s < SS; ++s) {
        float xv = xb[(size_t)s * NN];
#pragma unroll
        for (int e = 0; e < EE; ++e) {
            ai[e] = fmaf(xv, sW[e * 2 * SS + s], ai[e]);
            aj[e] = fmaf(xv, sW[e * 2 * SS + SS + s], aj[e]);
        }
    }

    float* op = tip + (size_t)gid * EE;
    float* oq = tjp + (size_t)gid * EE;
#pragma unroll
    for (int e = 0; e < EE; ++e) {
        op[e] = ai[e] + b_w[e];
        oq[e] = aj[e];
    }
}

// Kernel 2: fused scores + softmax + PV + sigmoid.
// One block per (b, i), 256 threads (4 waves).
__global__ __launch_bounds__(256) void attn_kernel(
    const float* __restrict__ x,    // (B, S, N)
    const float* __restrict__ tip,  // (B, N, E)
    const float* __restrict__ tjp,  // (B, N, E)
    const float* __restrict__ Wa,   // (E,)
    const float* __restrict__ b_a,  // scalar
    float* __restrict__ out0,       // (B, S, N)  h transposed
    float* __restrict__ out1)       // (B, N, N)  attention
{
    int b = blockIdx.x >> 9;
    int i = blockIdx.x & (NN - 1);
    int t = threadIdx.x;

    __shared__ float s_ti[EE];
    __shared__ float s_wa[EE];
    __shared__ float sc[NN];
    __shared__ float red[8];
    __shared__ float hpart[SS][5]; // padded

    if (t < EE) {
        s_ti[t] = tip[((size_t)(b * NN + i)) * EE + t];
        s_wa[t] = Wa[t];
    }
    __syncthreads();

    float ba = b_a[0];

    // ---- scores: each thread does j = t and j = t + 256 ----
    float ev[2];
#pragma unroll
    for (int r = 0; r < 2; ++r) {
        int j = t + r * 256;
        const float4* tj4 = (const float4*)(tjp + ((size_t)(b * NN + j)) * EE);
        float acc = ba;
#pragma unroll
        for (int q = 0; q < EE / 4; ++q) {
            float4 v4 = tj4[q];
            float p0 = s_ti[q * 4 + 0] + v4.x;
            float p1 = s_ti[q * 4 + 1] + v4.y;
            float p2 = s_ti[q * 4 + 2] + v4.z;
            float p3 = s_ti[q * 4 + 3] + v4.w;
            p0 = (p0 > 0.f) ? p0 : 0.2f * p0;
            p1 = (p1 > 0.f) ? p1 : 0.2f * p1;
            p2 = (p2 > 0.f) ? p2 : 0.2f * p2;
            p3 = (p3 > 0.f) ? p3 : 0.2f * p3;
            acc = fmaf(p0, s_wa[q * 4 + 0], acc);
            acc = fmaf(p1, s_wa[q * 4 + 1], acc);
            acc = fmaf(p2, s_wa[q * 4 + 2], acc);
            acc = fmaf(p3, s_wa[q * 4 + 3], acc);
        }
        ev[r] = acc;
    }

    // ---- softmax over 512 values ----
    float m = fmaxf(ev[0], ev[1]);
#pragma unroll
    for (int off = 32; off >= 1; off >>= 1)
        m = fmaxf(m, __shfl_xor(m, off));
    if ((t & 63) == 0) red[t >> 6] = m;
    __syncthreads();
    float M = fmaxf(fmaxf(red[0], red[1]), fmaxf(red[2], red[3]));

    float p0 = __expf(ev[0] - M);
    float p1 = __expf(ev[1] - M);
    float psum = p0 + p1;
#pragma unroll
    for (int off = 32; off >= 1; off >>= 1)
        psum += __shfl_xor(psum, off);
    __syncthreads(); // protect red[] WAR
    if ((t & 63) == 0) red[4 + (t >> 6)] = psum;
    __syncthreads();
    float SUM = (red[4] + red[5]) + (red[6] + red[7]);
    float inv = 1.0f / SUM;

    float a0 = p0 * inv;
    float a1 = p1 * inv;
    sc[t] = a0;
    sc[t + 256] = a1;
    // coalesced attention row write
    float* orow = out1 + ((size_t)(b * NN + i)) * NN;
    orow[t] = a0;
    orow[t + 256] = a1;
    __syncthreads();

    // ---- PV: h[s] = sigmoid( sum_j attn[j] * x[b,s,j] ) ----
    int s = t & (SS - 1);
    int c = t >> 6; // 4 chunks of 128 j
    const float* xr = x + ((size_t)(b * SS + s)) * NN + c * 128;
    float acc = 0.f;
#pragma unroll
    for (int k = 0; k < 128; k += 4) {
        float4 xv = *(const float4*)(xr + k);
        int jb = c * 128 + k;
        acc = fmaf(sc[jb + 0], xv.x, acc);
        acc = fmaf(sc[jb + 1], xv.y, acc);
        acc = fmaf(sc[jb + 2], xv.z, acc);
        acc = fmaf(sc[jb + 3], xv.w, acc);
    }
    hpart[s][c] = acc;
    __syncthreads();

    if (t < SS) {
        float h = (hpart[t][0] + hpart[t][1]) + (hpart[t][2] + hpart[t][3]);
        float sg = 1.0f / (1.0f + __expf(-h));
        out0[((size_t)(b * SS + t)) * NN + i] = sg;
    }
}

extern "C" void kernel_launch(void* const* d_in, const int* in_sizes, int n_in,
                              void* d_out, int out_size, void* d_ws, size_t ws_size,
                              hipStream_t stream) {
    const float* x   = (const float*)d_in[0];
    const float* W   = (const float*)d_in[1];
    const float* b_w = (const float*)d_in[2];
    const float* Wa  = (const float*)d_in[3];
    const float* b_a = (const float*)d_in[4];

    float* out0 = (float*)d_out;                       // (B,S,N) = 262144
    float* out1 = (float*)d_out + (size_t)BB * SS * NN; // (B,N,N) = 2097152

    float* tip = (float*)d_ws;                          // B*N*E floats
    float* tjp = tip + (size_t)BB * NN * EE;            // B*N*E floats

    proj_kernel<<<(BB * NN) / 256, 256, 0, stream>>>(x, W, b_w, tip, tjp);
    attn_kernel<<<BB * NN, 256, 0, stream>>>(x, tip, tjp, Wa, b_a, out0, out1);
}

// Round 2
// 41.349 us; speedup vs baseline: 3.7681x; 3.7681x over previous
//
#include <hip/hip_runtime.h>
#include <math.h>

#define BB 8
#define SS 64
#define NN 512
#define EE 32
#define IT 16

// proj: tip[b][e][n] = sum_s x[b][s][n]*W[e][s] + b_w[e]   (layout B,E,N)
//       tjp[b][e][n] = sum_s x[b][s][n]*W[e][64+s]
__global__ __launch_bounds__(256) void proj_kernel(
    const float* __restrict__ x,
    const float* __restrict__ W,
    const float* __restrict__ b_w,
    float* __restrict__ tip,
    float* __restrict__ tjp)
{
    __shared__ float sW[SS][65];   // [s][eo], pad -> conflict-free
    __shared__ float sx[SS][16];   // x tile [s][n_local]
    const int t = threadIdx.x;
    const int b = blockIdx.x >> 5;
    const int n0 = (blockIdx.x & 31) << 4;

#pragma unroll
    for (int r = 0; r < 4; ++r) {          // stage W (4096 floats), coalesced
        int idx = r * 1024 + t * 4;
        float4 w4 = *(const float4*)(W + idx);
        int e = idx >> 7;
        int sp = idx & 127;
        int eo = ((sp >> 6) << 5) | e;     // 0..31 = ti, 32..63 = tj
        int s0 = sp & 63;
        sW[s0 + 0][eo] = w4.x;
        sW[s0 + 1][eo] = w4.y;
        sW[s0 + 2][eo] = w4.z;
        sW[s0 + 3][eo] = w4.w;
    }
#pragma unroll
    for (int r = 0; r < 4; ++r) {          // stage x tile (1024 floats)
        int idx = r * 256 + t;
        int s = idx >> 4, nn = idx & 15;
        sx[s][nn] = x[((size_t)(b * SS + s)) * NN + n0 + nn];
    }
    __syncthreads();

    const int eo = t & 63;                  // output row (e + 32*half)
    const int ng = t >> 6;                  // n-quad
    float a0 = 0.f, a1 = 0.f, a2 = 0.f, a3 = 0.f;
#pragma unroll 8
    for (int s = 0; s < SS; ++s) {
        float wv = sW[s][eo];                              // conflict-free
        float4 xv = ((const float4*)&sx[s][0])[ng];        // wave-uniform bcast
        a0 = fmaf(wv, xv.x, a0);
        a1 = fmaf(wv, xv.y, a1);
        a2 = fmaf(wv, xv.z, a2);
        a3 = fmaf(wv, xv.w, a3);
    }
    const int e = eo & 31;
    float bias = (eo < EE) ? b_w[e] : 0.f;
    float* dst = (eo < EE) ? tip : tjp;
    float4 o = make_float4(a0 + bias, a1 + bias, a2 + bias, a3 + bias);
    *(float4*)(dst + ((size_t)(b * EE + e)) * NN + n0 + (ng << 2)) = o;
}

// attn: one block per (b, 16-i tile), 512 threads (8 waves).
__global__ __launch_bounds__(512) void attn_kernel(
    const float* __restrict__ x,
    const float* __restrict__ tip,
    const float* __restrict__ tjp,
    const float* __restrict__ Wa,
    float* __restrict__ out0,
    float* __restrict__ out1)
{
    __shared__ float s_ti[EE][IT];     // [e][ii]  (includes b_w)
    __shared__ float s_wa[EE];
    __shared__ float scT[NN][IT];      // [j][ii]  attention, transposed
    __shared__ float sx[SS][129];      // x chunk [s][j_local], pad 129
    __shared__ float s_red[8][IT];     // per-wave partials
    __shared__ float hp[2][SS][IT];    // PV half-partials

    const int t = threadIdx.x;
    const int lane = t & 63;
    const int wvid = t >> 6;
    const int b = blockIdx.x >> 5;
    const int i0 = (blockIdx.x & 31) << 4;

    {
        int e = t >> 4, ii = t & 15;   // 512 == EE*IT
        s_ti[e][ii] = tip[((size_t)(b * EE + e)) * NN + i0 + ii];
    }
    if (t < EE) s_wa[t] = Wa[t];
    __syncthreads();

    // ---- scores: thread owns column j = t, 16 row accumulators ----
    float acc[IT];
#pragma unroll
    for (int ii = 0; ii < IT; ++ii) acc[ii] = 0.f;

    const float* tjb = tjp + (size_t)b * EE * NN + t;
#pragma unroll 8
    for (int e = 0; e < EE; ++e) {
        float tjv = tjb[(size_t)e * NN];   // coalesced
        float wa = s_wa[e];
#pragma unroll
        for (int q = 0; q < 4; ++q) {
            float4 tv = ((const float4*)&s_ti[e][0])[q];   // bcast
            float p;
            p = tv.x + tjv; p = fmaxf(p, 0.2f * p); acc[q*4+0] = fmaf(p, wa, acc[q*4+0]);
            p = tv.y + tjv; p = fmaxf(p, 0.2f * p); acc[q*4+1] = fmaf(p, wa, acc[q*4+1]);
            p = tv.z + tjv; p = fmaxf(p, 0.2f * p); acc[q*4+2] = fmaf(p, wa, acc[q*4+2]);
            p = tv.w + tjv; p = fmaxf(p, 0.2f * p); acc[q*4+3] = fmaf(p, wa, acc[q*4+3]);
        }
    }
    // (b_a dropped: softmax-invariant)

    // ---- softmax over j (reductions across the 512 threads) ----
    float red[IT];
#pragma unroll
    for (int ii = 0; ii < IT; ++ii) {       // wave max per row
        float v = acc[ii];
#pragma unroll
        for (int off = 32; off >= 1; off >>= 1) v = fmaxf(v, __shfl_xor(v, off));
        red[ii] = v;
    }
    if (lane == 0) {
#pragma unroll
        for (int q = 0; q < 4; ++q)
            ((float4*)&s_red[wvid][0])[q] = make_float4(red[4*q], red[4*q+1], red[4*q+2], red[4*q+3]);
    }
    __syncthreads();
    float M[IT];
#pragma unroll
    for (int q = 0; q < 4; ++q) {
        float4 m4 = ((const float4*)&s_red[0][0])[q];
#pragma unroll
        for (int u = 1; u < 8; ++u) {
            float4 r4 = ((const float4*)&s_red[u][0])[q];
            m4.x = fmaxf(m4.x, r4.x); m4.y = fmaxf(m4.y, r4.y);
            m4.z = fmaxf(m4.z, r4.z); m4.w = fmaxf(m4.w, r4.w);
        }
        M[4*q+0] = m4.x; M[4*q+1] = m4.y; M[4*q+2] = m4.z; M[4*q+3] = m4.w;
    }

    float pr[IT];
#pragma unroll
    for (int ii = 0; ii < IT; ++ii) pr[ii] = __expf(acc[ii] - M[ii]);

#pragma unroll
    for (int ii = 0; ii < IT; ++ii) {       // wave sum per row
        float v = pr[ii];
#pragma unroll
        for (int off = 32; off >= 1; off >>= 1) v += __shfl_xor(v, off);
        red[ii] = v;
    }
    __syncthreads();                         // done reading maxima
    if (lane == 0) {
#pragma unroll
        for (int q = 0; q < 4; ++q)
            ((float4*)&s_red[wvid][0])[q] = make_float4(red[4*q], red[4*q+1], red[4*q+2], red[4*q+3]);
    }
    __syncthreads();
#pragma unroll
    for (int q = 0; q < 4; ++q) {
        float4 m4 = ((const float4*)&s_red[0][0])[q];
#pragma unroll
        for (int u = 1; u < 8; ++u) {
            float4 r4 = ((const float4*)&s_red[u][0])[q];
            m4.x += r4.x; m4.y += r4.y; m4.z += r4.z; m4.w += r4.w;
        }
        M[4*q+0] = m4.x; M[4*q+1] = m4.y; M[4*q+2] = m4.z; M[4*q+3] = m4.w;
    }

    float att[IT];
#pragma unroll
    for (int ii = 0; ii < IT; ++ii) att[ii] = pr[ii] * (1.0f / M[ii]);

    // write attention (coalesced: lanes = consecutive j)
    float* orow = out1 + ((size_t)(b * NN + i0)) * NN + t;
#pragma unroll
    for (int ii = 0; ii < IT; ++ii) orow[(size_t)ii * NN] = att[ii];

    // transposed copy to LDS for PV
#pragma unroll
    for (int q = 0; q < 4; ++q)
        ((float4*)&scT[t][0])[q] = make_float4(att[4*q], att[4*q+1], att[4*q+2], att[4*q+3]);

    // ---- PV: h[s][ii] = sum_j att[ii][j] * x[b][s][j] ----
    float pv0 = 0.f, pv1 = 0.f, pv2 = 0.f, pv3 = 0.f;
    const int s = t & 63;
    const int ig = (t >> 6) & 3;
    const int hf = t >> 8;
    for (int c = 0; c < 4; ++c) {
        __syncthreads();                    // protect sx (and scT on c=0)
#pragma unroll
        for (int r = 0; r < 4; ++r) {       // stage x[:, c*128..+128] coalesced
            int idx = r * 512 + t;
            int ss = idx >> 5, jj = (idx & 31) << 2;
            float4 xv = *(const float4*)(x + ((size_t)(b * SS + ss)) * NN + (c << 7) + jj);
            sx[ss][jj]     = xv.x;
            sx[ss][jj + 1] = xv.y;
            sx[ss][jj + 2] = xv.z;
            sx[ss][jj + 3] = xv.w;
        }
        __syncthreads();
        const int jb = (c << 7) + (hf << 6);
        const int jl = hf << 6;
#pragma unroll 8
        for (int u = 0; u < 64; ++u) {
            float xval = sx[s][jl + u];                          // conflict-free (pad 129)
            float4 a4 = ((const float4*)&scT[jb + u][0])[ig];    // bcast
            pv0 = fmaf(a4.x, xval, pv0);
            pv1 = fmaf(a4.y, xval, pv1);
            pv2 = fmaf(a4.z, xval, pv2);
            pv3 = fmaf(a4.w, xval, pv3);
        }
    }
    ((float4*)&hp[hf][s][0])[ig] = make_float4(pv0, pv1, pv2, pv3);
    __syncthreads();
    {
        const int ii = t & 15;
        const int sbase = t >> 4;           // 0..31
#pragma unroll
        for (int rr = 0; rr < 2; ++rr) {
            int ss2 = sbase + rr * 32;
            float h = hp[0][ss2][ii] + hp[1][ss2][ii];
            float sg = 1.0f / (1.0f + __expf(-h));
            out0[((size_t)(b * SS + ss2)) * NN + i0 + ii] = sg;
        }
    }
}

extern "C" void kernel_launch(void* const* d_in, const int* in_sizes, int n_in,
                              void* d_out, int out_size, void* d_ws, size_t ws_size,
                              hipStream_t stream) {
    const float* x   = (const float*)d_in[0];
    const float* W   = (const float*)d_in[1];
    const float* b_w = (const float*)d_in[2];
    const float* Wa  = (const float*)d_in[3];

    float* out0 = (float*)d_out;                        // (B,S,N)
    float* out1 = (float*)d_out + (size_t)BB * SS * NN; // (B,N,N)

    float* tip = (float*)d_ws;                          // (B,E,N)
    float* tjp = tip + (size_t)BB * EE * NN;            // (B,E,N)

    proj_kernel<<<BB * (NN / 16), 256, 0, stream>>>(x, W, b_w, tip, tjp);
    attn_kernel<<<BB * (NN / IT), 512, 0, stream>>>(x, tip, tjp, Wa, out0, out1);
}

// Round 3
// 23.592 us; speedup vs baseline: 6.6043x; 1.7527x over previous
//
#include <hip/hip_runtime.h>
#include <math.h>

#define BB 8
#define SS 64
#define NN 512
#define EE 32
#define IT 16

// position of element i within swizzled scT row j (quad-XOR, bank-spread)
__device__ __forceinline__ int swz(int i, int j) {
    return (((i >> 2) ^ ((j >> 3) & 3)) << 2) | (i & 3);
}

// proj: tip[b][e][n] = ti'(= x^T W_i^T + b_w), tjp[b][e][n] = tj (layout B,E,N)
//       cip[b][n] = sum_e Wa[e]*ti'[n][e];  djp[b][n] = sum_e Wa[e]*tj[n][e]
__global__ __launch_bounds__(256) void proj_kernel(
    const float* __restrict__ x, const float* __restrict__ W,
    const float* __restrict__ b_w, const float* __restrict__ Wa,
    float* __restrict__ tip, float* __restrict__ tjp,
    float* __restrict__ cip, float* __restrict__ djp)
{
    __shared__ float sW[SS][65];
    const int t = threadIdx.x;
    const int b = blockIdx.x >> 5;
    const int n0 = (blockIdx.x & 31) << 4;

#pragma unroll
    for (int r = 0; r < 4; ++r) {   // stage W (4096 floats) as [s][eo]
        int idx = r * 1024 + t * 4;
        float4 w4 = *(const float4*)(W + idx);
        int e = idx >> 7;
        int sp = idx & 127;
        int eo = ((sp >> 6) << 5) | e;   // 0..31 ti, 32..63 tj
        int s0 = sp & 63;
        sW[s0 + 0][eo] = w4.x;
        sW[s0 + 1][eo] = w4.y;
        sW[s0 + 2][eo] = w4.z;
        sW[s0 + 3][eo] = w4.w;
    }
    __syncthreads();

    const int eo = t & 63;
    const int ng = t >> 6;
    const float* xb = x + (size_t)b * SS * NN + n0 + (ng << 2);
    float a0 = 0.f, a1 = 0.f, a2 = 0.f, a3 = 0.f;
#pragma unroll 8
    for (int s = 0; s < SS; ++s) {
        float wv = sW[s][eo];                       // conflict-free
        float4 xv = *(const float4*)(xb + (size_t)s * NN);  // wave-uniform bcast
        a0 = fmaf(wv, xv.x, a0);
        a1 = fmaf(wv, xv.y, a1);
        a2 = fmaf(wv, xv.z, a2);
        a3 = fmaf(wv, xv.w, a3);
    }
    const int e = eo & 31;
    const bool isI = eo < EE;
    float bias = isI ? b_w[e] : 0.f;
    a0 += bias; a1 += bias; a2 += bias; a3 += bias;
    float* dst = isI ? tip : tjp;
    *(float4*)(dst + ((size_t)(b * EE + e)) * NN + n0 + (ng << 2)) =
        make_float4(a0, a1, a2, a3);

    // rank-1 terms: reduce wa*val over each 32-lane half (xor<32 keeps halves apart)
    float wa = Wa[e];
    float r0 = wa * a0, r1 = wa * a1, r2 = wa * a2, r3 = wa * a3;
#pragma unroll
    for (int off = 1; off <= 16; off <<= 1) {
        r0 += __shfl_xor(r0, off);
        r1 += __shfl_xor(r1, off);
        r2 += __shfl_xor(r2, off);
        r3 += __shfl_xor(r3, off);
    }
    if (eo == 0)
        *(float4*)(cip + (size_t)b * NN + n0 + (ng << 2)) = make_float4(r0, r1, r2, r3);
    if (eo == 32)
        *(float4*)(djp + (size_t)b * NN + n0 + (ng << 2)) = make_float4(r0, r1, r2, r3);
}

// attn: block = (b, 16-i tile), 512 threads (8 waves)
__global__ __launch_bounds__(512, 2) void attn_kernel(
    const float* __restrict__ x,
    const float* __restrict__ tip,
    const float* __restrict__ tjp,
    const float* __restrict__ cip,
    const float* __restrict__ djp,
    const float* __restrict__ Wa,
    float* __restrict__ out0,
    float* __restrict__ out1)
{
    __shared__ float s_tiT[IT][36];           // [i][e], padded
    __shared__ float scT[NN][20];             // swizzled pr [j][i]
    __shared__ float red1[8][17];             // per-wave row partials
    __shared__ float s_M[IT];
    __shared__ float s_inv[IT];
    __shared__ __align__(16) float ubuf[EE * NN];   // union: stj[32][512] / hp[8][64][20]

    float (*stj)[NN] = (float (*)[NN])ubuf;

    const int t = threadIdx.x;
    const int b = blockIdx.x >> 5;
    const int i0 = (blockIdx.x & 31) << 4;

    // ---- staging ----
    {
        int e = t >> 4, ii = t & 15;
        s_tiT[ii][e] = tip[((size_t)(b * EE + e)) * NN + i0 + ii];
    }
    {
        const float4* src = (const float4*)(tjp + (size_t)b * EE * NN);
        float4* dst4 = (float4*)ubuf;
#pragma unroll
        for (int r = 0; r < 8; ++r) dst4[r * 512 + t] = src[r * 512 + t];
    }
    __syncthreads();

    // ---- scores: thread owns i in {2ip, 2ip+1}, j in [jc*8, jc*8+8) ----
    const int ip = t & 7;
    const int jc = t >> 3;
    const int jb0 = jc << 3;
    const int ia = 2 * ip, ibb = 2 * ip + 1;

    float rti0[EE], rti1[EE];
#pragma unroll
    for (int q = 0; q < 8; ++q) {
        float4 v = *(const float4*)(&s_tiT[ia][q << 2]);
        rti0[4 * q + 0] = v.x; rti0[4 * q + 1] = v.y;
        rti0[4 * q + 2] = v.z; rti0[4 * q + 3] = v.w;
        float4 w = *(const float4*)(&s_tiT[ibb][q << 2]);
        rti1[4 * q + 0] = w.x; rti1[4 * q + 1] = w.y;
        rti1[4 * q + 2] = w.z; rti1[4 * q + 3] = w.w;
    }

    float acc0[8], acc1[8];
#pragma unroll
    for (int k = 0; k < 8; ++k) { acc0[k] = 0.f; acc1[k] = 0.f; }

#pragma unroll
    for (int e = 0; e < EE; ++e) {
        float wa = Wa[e];                          // uniform -> s_load
        float t0 = rti0[e], t1 = rti1[e];
        float4 ja = *(const float4*)(&stj[e][jb0]);
        float4 jb = *(const float4*)(&stj[e][jb0 + 4]);
        float tj8[8] = {ja.x, ja.y, ja.z, ja.w, jb.x, jb.y, jb.z, jb.w};
#pragma unroll
        for (int k = 0; k < 8; ++k) {
            float p0 = fmaxf(t0 + tj8[k], 0.f);
            acc0[k] = fmaf(p0, wa, acc0[k]);
            float p1 = fmaxf(t1 + tj8[k], 0.f);
            acc1[k] = fmaf(p1, wa, acc1[k]);
        }
    }

    // epilogue: sc = 0.8*acc + 0.2*(Ci + dj)
    float dj8[8];
    {
        float4 d0 = *(const float4*)(djp + (size_t)b * NN + jb0);
        float4 d1 = *(const float4*)(djp + (size_t)b * NN + jb0 + 4);
        dj8[0] = d0.x; dj8[1] = d0.y; dj8[2] = d0.z; dj8[3] = d0.w;
        dj8[4] = d1.x; dj8[5] = d1.y; dj8[6] = d1.z; dj8[7] = d1.w;
    }
    float c0 = 0.2f * cip[(size_t)b * NN + i0 + ia];
    float c1 = 0.2f * cip[(size_t)b * NN + i0 + ibb];
    float sc0[8], sc1[8];
#pragma unroll
    for (int k = 0; k < 8; ++k) {
        sc0[k] = fmaf(0.8f, acc0[k], fmaf(0.2f, dj8[k], c0));
        sc1[k] = fmaf(0.8f, acc1[k], fmaf(0.2f, dj8[k], c1));
    }

    // ---- softmax: register + shuffle reductions ----
    float m0 = sc0[0], m1 = sc1[0];
#pragma unroll
    for (int k = 1; k < 8; ++k) { m0 = fmaxf(m0, sc0[k]); m1 = fmaxf(m1, sc1[k]); }
#pragma unroll
    for (int off = 8; off <= 32; off <<= 1) {
        m0 = fmaxf(m0, __shfl_xor(m0, off));
        m1 = fmaxf(m1, __shfl_xor(m1, off));
    }
    const int wv = t >> 6;
    if ((t & 56) == 0) { red1[wv][ia] = m0; red1[wv][ibb] = m1; }
    __syncthreads();
    if (t < IT) {
        float M = red1[0][t];
#pragma unroll
        for (int g = 1; g < 8; ++g) M = fmaxf(M, red1[g][t]);
        s_M[t] = M;
    }
    __syncthreads();

    float M0 = s_M[ia], M1 = s_M[ibb];
    float pr0[8], pr1[8];
#pragma unroll
    for (int k = 0; k < 8; ++k) {
        pr0[k] = __expf(sc0[k] - M0);
        pr1[k] = __expf(sc1[k] - M1);
    }
    // write pr (unnormalized) to swizzled scT for PV
#pragma unroll
    for (int k = 0; k < 8; ++k) {
        int j = jb0 + k;
        scT[j][swz(ia, j)] = pr0[k];
        scT[j][swz(ibb, j)] = pr1[k];
    }
    float q0 = 0.f, q1 = 0.f;
#pragma unroll
    for (int k = 0; k < 8; ++k) { q0 += pr0[k]; q1 += pr1[k]; }
#pragma unroll
    for (int off = 8; off <= 32; off <<= 1) {
        q0 += __shfl_xor(q0, off);
        q1 += __shfl_xor(q1, off);
    }
    if ((t & 56) == 0) { red1[wv][ia] = q0; red1[wv][ibb] = q1; }
    __syncthreads();
    if (t < IT) {
        float S = 0.f;
#pragma unroll
        for (int g = 0; g < 8; ++g) S += red1[g][t];
        s_inv[t] = 1.0f / S;
    }
    __syncthreads();

    // ---- attention output (coalesced 128B segments) ----
    {
        float v0 = s_inv[ia], v1 = s_inv[ibb];
        float* r0p = out1 + ((size_t)(b * NN + i0 + ia)) * NN + jb0;
        float* r1p = out1 + ((size_t)(b * NN + i0 + ibb)) * NN + jb0;
        *(float4*)(r0p)     = make_float4(pr0[0]*v0, pr0[1]*v0, pr0[2]*v0, pr0[3]*v0);
        *(float4*)(r0p + 4) = make_float4(pr0[4]*v0, pr0[5]*v0, pr0[6]*v0, pr0[7]*v0);
        *(float4*)(r1p)     = make_float4(pr1[0]*v1, pr1[1]*v1, pr1[2]*v1, pr1[3]*v1);
        *(float4*)(r1p + 4) = make_float4(pr1[4]*v1, pr1[5]*v1, pr1[6]*v1, pr1[7]*v1);
    }

    // ---- PV: h[s][i] = inv[i] * sum_j pr[i][j]*x[b][s][j]; x direct from global ----
    const int jw = t & 3, sq = (t >> 2) & 7, ih = (t >> 5) & 1, w8 = t >> 6;
    float pacc[8][8];
#pragma unroll
    for (int r = 0; r < 8; ++r)
#pragma unroll
        for (int c = 0; c < 8; ++c) pacc[r][c] = 0.f;

    const float* xbb = x + (size_t)b * SS * NN;
#pragma unroll
    for (int uu = 0; uu < 4; ++uu) {
        const int jb = uu * 128 + w8 * 16 + jw * 4;
        float xq[8][4];
#pragma unroll
        for (int r = 0; r < 8; ++r) {
            float4 xv = *(const float4*)(xbb + (size_t)(sq + 8 * r) * NN + jb);
            xq[r][0] = xv.x; xq[r][1] = xv.y; xq[r][2] = xv.z; xq[r][3] = xv.w;
        }
#pragma unroll
        for (int v = 0; v < 4; ++v) {
            int j2 = jb + v;
            int key = (j2 >> 3) & 3;
            float4 pA4 = *(const float4*)(&scT[j2][((2 * ih) ^ key) << 2]);
            float4 pB4 = *(const float4*)(&scT[j2][((2 * ih + 1) ^ key) << 2]);
            float pA[4] = {pA4.x, pA4.y, pA4.z, pA4.w};
            float pB[4] = {pB4.x, pB4.y, pB4.z, pB4.w};
#pragma unroll
            for (int r = 0; r < 8; ++r) {
                float xv = xq[r][v];
#pragma unroll
                for (int c = 0; c < 4; ++c) {
                    pacc[r][c]     = fmaf(xv, pA[c], pacc[r][c]);
                    pacc[r][4 + c] = fmaf(xv, pB[c], pacc[r][4 + c]);
                }
            }
        }
    }

    // 4-lane (jw) reduction on the VALU pipe via DPP quad_perm butterflies
#pragma unroll
    for (int r = 0; r < 8; ++r)
#pragma unroll
        for (int c = 0; c < 8; ++c) {
            float v = pacc[r][c];
            v += __int_as_float(__builtin_amdgcn_mov_dpp(__float_as_int(v), 0xB1, 0xF, 0xF, true));
            v += __int_as_float(__builtin_amdgcn_mov_dpp(__float_as_int(v), 0x4E, 0xF, 0xF, true));
            pacc[r][c] = v;
        }
    if (jw == 0) {
#pragma unroll
        for (int r = 0; r < 8; ++r) {
            int s = sq + 8 * r;
            float* hq = &ubuf[(size_t)(w8 * SS + s) * 20 + ih * 8];
            *(float4*)(hq)     = make_float4(pacc[r][0], pacc[r][1], pacc[r][2], pacc[r][3]);
            *(float4*)(hq + 4) = make_float4(pacc[r][4], pacc[r][5], pacc[r][6], pacc[r][7]);
        }
    }
    __syncthreads();

    // ---- final: sum 8 wave-partials, scale, sigmoid, store ----
    {
        int i = t & 15, sp = t >> 4;
        float vi = s_inv[i];
#pragma unroll
        for (int p = 0; p < 2; ++p) {
            int s = sp + 32 * p;
            float h = 0.f;
#pragma unroll
            for (int wq = 0; wq < 8; ++wq) h += ubuf[(size_t)(wq * SS + s) * 20 + i];
            h *= vi;
            out0[((size_t)(b * SS + s)) * NN + i0 + i] = 1.0f / (1.0f + __expf(-h));
        }
    }
}

extern "C" void kernel_launch(void* const* d_in, const int* in_sizes, int n_in,
                              void* d_out, int out_size, void* d_ws, size_t ws_size,
                              hipStream_t stream) {
    const float* x   = (const float*)d_in[0];
    const float* W   = (const float*)d_in[1];
    const float* b_w = (const float*)d_in[2];
    const float* Wa  = (const float*)d_in[3];

    float* out0 = (float*)d_out;                         // (B,S,N)
    float* out1 = (float*)d_out + (size_t)BB * SS * NN;  // (B,N,N)

    float* tip = (float*)d_ws;                           // (B,E,N)
    float* tjp = tip + (size_t)BB * EE * NN;             // (B,E,N)
    float* cip = tjp + (size_t)BB * EE * NN;             // (B,N)
    float* djp = cip + (size_t)BB * NN;                  // (B,N)

    proj_kernel<<<BB * (NN / 16), 256, 0, stream>>>(x, W, b_w, Wa, tip, tjp, cip, djp);
    attn_kernel<<<BB * (NN / IT), 512, 0, stream>>>(x, tip, tjp, cip, djp, Wa, out0, out1);
}